// Round 1
// baseline (585.010 us; speedup 1.0000x reference)
//
#include <hip/hip_runtime.h>
#include <hip/hip_bf16.h>
#include <math.h>

typedef __bf16 bf16_t;
typedef __attribute__((ext_vector_type(8))) __bf16 bf16x8;
typedef __attribute__((ext_vector_type(4))) __bf16 bf16x4;
typedef __attribute__((ext_vector_type(4))) float f32x4;

typedef __attribute__((address_space(1))) unsigned as1u;
typedef __attribute__((address_space(3))) unsigned as3u;

// async global->LDS, 16B per lane; LDS dest must be wave-uniform base (+lane*16 implicit)
__device__ __forceinline__ void async_copy16(bf16_t* lds, const bf16_t* g) {
  __builtin_amdgcn_global_load_lds((as1u*)g, (as3u*)lds, 16, 0, 0);
}

__device__ __forceinline__ float gelu_exact(float t) {
  return 0.5f * t * (1.0f + erff(t * 0.70710678118654752f));
}

// ---------------------------------------------------------------- cast f32->bf16
__global__ __launch_bounds__(256)
void cast_kernel(const float* __restrict__ w, bf16_t* __restrict__ o, int n) {
  int i = (blockIdx.x * 256 + threadIdx.x) * 4;
  if (i < n) {
    float4 v = *(const float4*)(w + i);
    bf16x4 t;
    t[0] = (bf16_t)v.x; t[1] = (bf16_t)v.y; t[2] = (bf16_t)v.z; t[3] = (bf16_t)v.w;
    *(bf16x4*)(o + i) = t;
  }
}

// ---------------------------------------------------------------- LN1 + in-mask -> bf16
__global__ __launch_bounds__(256)
void ln1_kernel(const float* __restrict__ x, const float* __restrict__ gam,
                const float* __restrict__ bet, const int* __restrict__ em,
                bf16_t* __restrict__ xn) {
  const int row = blockIdx.x, tid = threadIdx.x;
  const float4 v = ((const float4*)(x + (size_t)row * 1024))[tid];
  float s = v.x + v.y + v.z + v.w;
  float sq = v.x * v.x + v.y * v.y + v.z * v.z + v.w * v.w;
  #pragma unroll
  for (int off = 1; off < 64; off <<= 1) { s += __shfl_xor(s, off); sq += __shfl_xor(sq, off); }
  __shared__ float red[8];
  const int wave = tid >> 6, lane = tid & 63;
  if (lane == 0) { red[wave] = s; red[4 + wave] = sq; }
  __syncthreads();
  s = red[0] + red[1] + red[2] + red[3];
  sq = red[4] + red[5] + red[6] + red[7];
  const float mean = s * (1.0f / 1024.0f);
  const float var = sq * (1.0f / 1024.0f) - mean * mean;
  const float rstd = rsqrtf(var + 1e-5f);
  const int din = 1024 >> (3 - em[row]);
  const float4 gv = ((const float4*)gam)[tid];
  const float4 bv = ((const float4*)bet)[tid];
  const int c0 = tid * 4;
  float vf[4] = {v.x, v.y, v.z, v.w};
  float gf[4] = {gv.x, gv.y, gv.z, gv.w};
  float bvf[4] = {bv.x, bv.y, bv.z, bv.w};
  bf16x4 o;
  #pragma unroll
  for (int i = 0; i < 4; ++i) {
    float t = (vf[i] - mean) * rstd * gf[i] + bvf[i];
    o[i] = (c0 + i < din) ? (bf16_t)t : (bf16_t)0.0f;
  }
  *(bf16x4*)(xn + (size_t)row * 1024 + c0) = o;
}

// ---------------------------------------------------------------- LN2 over k and v, in place (bf16)
__global__ __launch_bounds__(256)
void ln2_kernel(bf16_t* __restrict__ kv, const float* __restrict__ gam,
                const float* __restrict__ bet) {
  const int row = blockIdx.x, tid = threadIdx.x;
  bf16_t* base = kv + (size_t)row * 2048;
  bf16x4 kk = *(const bf16x4*)(base + tid * 4);
  bf16x4 vv = *(const bf16x4*)(base + 1024 + tid * 4);
  float kf[4], vf[4];
  float ks = 0, ksq = 0, vs = 0, vsq = 0;
  #pragma unroll
  for (int i = 0; i < 4; ++i) {
    kf[i] = (float)kk[i]; ks += kf[i]; ksq += kf[i] * kf[i];
    vf[i] = (float)vv[i]; vs += vf[i]; vsq += vf[i] * vf[i];
  }
  #pragma unroll
  for (int off = 1; off < 64; off <<= 1) {
    ks += __shfl_xor(ks, off); ksq += __shfl_xor(ksq, off);
    vs += __shfl_xor(vs, off); vsq += __shfl_xor(vsq, off);
  }
  __shared__ float red[16];
  const int wave = tid >> 6, lane = tid & 63;
  if (lane == 0) { red[wave] = ks; red[4 + wave] = ksq; red[8 + wave] = vs; red[12 + wave] = vsq; }
  __syncthreads();
  ks = red[0] + red[1] + red[2] + red[3];
  ksq = red[4] + red[5] + red[6] + red[7];
  vs = red[8] + red[9] + red[10] + red[11];
  vsq = red[12] + red[13] + red[14] + red[15];
  const float mk = ks * (1.f / 1024.f), mv = vs * (1.f / 1024.f);
  const float rk = rsqrtf(ksq * (1.f / 1024.f) - mk * mk + 1e-5f);
  const float rv = rsqrtf(vsq * (1.f / 1024.f) - mv * mv + 1e-5f);
  const float4 gv = ((const float4*)gam)[tid];
  const float4 bv = ((const float4*)bet)[tid];
  float gf[4] = {gv.x, gv.y, gv.z, gv.w}, bvf[4] = {bv.x, bv.y, bv.z, bv.w};
  bf16x4 ko, vo;
  #pragma unroll
  for (int i = 0; i < 4; ++i) {
    ko[i] = (bf16_t)((kf[i] - mk) * rk * gf[i] + bvf[i]);
    vo[i] = (bf16_t)((vf[i] - mv) * rv * gf[i] + bvf[i]);
  }
  *(bf16x4*)(base + tid * 4) = ko;
  *(bf16x4*)(base + 1024 + tid * 4) = vo;
}

// ---------------------------------------------------------------- bf16 GEMM, C[m,o] = sum_k A[m,k]*W[o,k]
// 128x128 tile, BK=64, 4 waves (each 64x64), global_load_lds w/ inverse-swizzled source,
// XOR slot swizzle on ds_read_b128 (G4 / rule 21).
template<int EPI>
__global__ __launch_bounds__(256)
void gemm_bt(const bf16_t* __restrict__ A, const bf16_t* __restrict__ W, const int K,
             const float* __restrict__ bias,
             bf16_t* __restrict__ q_bf, bf16_t* __restrict__ kv_bf, bf16_t* __restrict__ h_bf,
             float* __restrict__ Z) {
  __shared__ bf16_t As[128 * 64];
  __shared__ bf16_t Bs[128 * 64];
  const int tid = threadIdx.x;
  const int wave = tid >> 6, lane = tid & 63;
  const int l15 = lane & 15, l4 = lane >> 4;
  const int bm = blockIdx.x, bn = blockIdx.y;
  const int wm = wave >> 1, wn = wave & 1;

  f32x4 acc[4][4] = {};

  const int rbase = tid >> 3;                 // LDS row within 32-row stripe
  const int ss = (tid & 7) ^ (rbase & 7);     // inverse-swizzled global 16B slot
  const bf16_t* Ag = A + (size_t)(bm * 128 + rbase) * K + ss * 8;
  const bf16_t* Wg = W + (size_t)(bn * 128 + rbase) * K + ss * 8;

  const int nkt = K >> 6;
  for (int kt = 0; kt < nkt; ++kt) {
    #pragma unroll
    for (int i = 0; i < 4; ++i) {
      async_copy16(As + (i * 256 + wave * 64) * 8, Ag + (size_t)i * 32 * K + kt * 64);
      async_copy16(Bs + (i * 256 + wave * 64) * 8, Wg + (size_t)i * 32 * K + kt * 64);
    }
    __syncthreads();
    #pragma unroll
    for (int ks = 0; ks < 2; ++ks) {
      bf16x8 a[4], b[4];
      #pragma unroll
      for (int mi = 0; mi < 4; ++mi) {
        const int r = wm * 64 + mi * 16 + l15;
        const int slot = (ks * 4 + l4) ^ (r & 7);
        a[mi] = *(const bf16x8*)(As + r * 64 + slot * 8);
      }
      #pragma unroll
      for (int ni = 0; ni < 4; ++ni) {
        const int r = wn * 64 + ni * 16 + l15;
        const int slot = (ks * 4 + l4) ^ (r & 7);
        b[ni] = *(const bf16x8*)(Bs + r * 64 + slot * 8);
      }
      #pragma unroll
      for (int mi = 0; mi < 4; ++mi)
        #pragma unroll
        for (int ni = 0; ni < 4; ++ni)
          acc[mi][ni] = __builtin_amdgcn_mfma_f32_16x16x32_bf16(a[mi], b[ni], acc[mi][ni], 0, 0, 0);
    }
    __syncthreads();
  }

  // epilogue; C/D layout: row=(lane>>4)*4+reg, col=lane&15 (m89-verified)
  #pragma unroll
  for (int mi = 0; mi < 4; ++mi) {
    #pragma unroll
    for (int ni = 0; ni < 4; ++ni) {
      const int gc = bn * 128 + wn * 64 + ni * 16 + l15;
      #pragma unroll
      for (int r = 0; r < 4; ++r) {
        const int gm = bm * 128 + wm * 64 + mi * 16 + l4 * 4 + r;
        const float c = acc[mi][ni][r];
        if (EPI == 0) {
          if (gc < 1024) {
            q_bf[(size_t)gm * 1024 + gc] = (bf16_t)c;
          } else if (gc < 3072) {
            kv_bf[(size_t)gm * 2048 + (gc - 1024)] = (bf16_t)c;
          } else {
            const float t = c + bias[gc - 3072];
            h_bf[(size_t)gm * 5120 + 1024 + (gc - 3072)] = (bf16_t)gelu_exact(t);
          }
        } else {
          Z[(size_t)gm * 2048 + gc] = c + bias[gc];
        }
      }
    }
  }
}

// ---------------------------------------------------------------- flash attention
// grid: (qt=16, bh=128); 4 waves x 16 q-rows; K swizzle-staged, V transposed at staging.
__global__ __launch_bounds__(256)
void attn_kernel(const bf16_t* __restrict__ qb, const bf16_t* __restrict__ kv,
                 bf16_t* __restrict__ hb) {
  __shared__ bf16_t Kl[64 * 64];
  __shared__ bf16_t Vt[64 * 72];     // [d][key], pad 8 -> 2-way (free)
  __shared__ bf16_t Pl[4][16 * 72];  // per-wave P tile [q][key]
  const int tid = threadIdx.x;
  const int wave = tid >> 6, lane = tid & 63;
  const int l15 = lane & 15, l4 = lane >> 4;
  const int qt = blockIdx.x, bh = blockIdx.y;
  const int bb = bh >> 4, head = bh & 15;
  const int tok0 = bb << 10;
  const int d0 = head << 6;

  const int qrow = tok0 + qt * 64 + wave * 16 + l15;
  const bf16x8 aq0 = *(const bf16x8*)(qb + (size_t)qrow * 1024 + d0 + l4 * 8);
  const bf16x8 aq1 = *(const bf16x8*)(qb + (size_t)qrow * 1024 + d0 + 32 + l4 * 8);

  f32x4 o[4] = {};
  float mrun[4] = {-1e30f, -1e30f, -1e30f, -1e30f};
  float lrun[4] = {0.f, 0.f, 0.f, 0.f};

  const int krb = tid >> 3;
  const int kss = (tid & 7) ^ (krb & 7);

  for (int kt = 0; kt < 16; ++kt) {
    const int krow0 = tok0 + kt * 64;
    #pragma unroll
    for (int i = 0; i < 2; ++i) {
      const int r = i * 32 + krb;
      async_copy16(Kl + (i * 256 + wave * 64) * 8,
                   kv + (size_t)(krow0 + r) * 2048 + d0 + kss * 8);
    }
    #pragma unroll
    for (int i = 0; i < 2; ++i) {
      const int key = i * 32 + (tid >> 3);
      const int dc = tid & 7;
      bf16x8 vvv = *(const bf16x8*)(kv + (size_t)(krow0 + key) * 2048 + 1024 + d0 + dc * 8);
      #pragma unroll
      for (int j = 0; j < 8; ++j) Vt[(dc * 8 + j) * 72 + key] = vvv[j];
    }
    __syncthreads();

    // S = Q K^T  (C: row=(l>>4)*4+r = q_local, col=l&15+16kc = key)
    f32x4 s[4] = {};
    #pragma unroll
    for (int ks = 0; ks < 2; ++ks) {
      const bf16x8 aqk = ks ? aq1 : aq0;
      #pragma unroll
      for (int kc = 0; kc < 4; ++kc) {
        const int r = kc * 16 + l15;
        const int slot = (ks * 4 + l4) ^ (r & 7);
        bf16x8 bk = *(const bf16x8*)(Kl + r * 64 + slot * 8);
        s[kc] = __builtin_amdgcn_mfma_f32_16x16x32_bf16(aqk, bk, s[kc], 0, 0, 0);
      }
    }
    // online softmax (scale 0.125), row-reduce over the 16 lanes of same l>>4
    #pragma unroll
    for (int r = 0; r < 4; ++r) {
      float mx = -1e30f;
      #pragma unroll
      for (int kc = 0; kc < 4; ++kc) mx = fmaxf(mx, s[kc][r]);
      mx = fmaxf(mx, __shfl_xor(mx, 1));
      mx = fmaxf(mx, __shfl_xor(mx, 2));
      mx = fmaxf(mx, __shfl_xor(mx, 4));
      mx = fmaxf(mx, __shfl_xor(mx, 8));
      mx *= 0.125f;
      const float mnew = fmaxf(mrun[r], mx);
      const float corr = __expf(mrun[r] - mnew);
      float ps = 0.f;
      #pragma unroll
      for (int kc = 0; kc < 4; ++kc) {
        const float p = __expf(s[kc][r] * 0.125f - mnew);
        ps += p;
        Pl[wave][(l4 * 4 + r) * 72 + kc * 16 + l15] = (bf16_t)p;
      }
      ps += __shfl_xor(ps, 1); ps += __shfl_xor(ps, 2);
      ps += __shfl_xor(ps, 4); ps += __shfl_xor(ps, 8);
      lrun[r] = lrun[r] * corr + ps;
      mrun[r] = mnew;
      o[0][r] *= corr; o[1][r] *= corr; o[2][r] *= corr; o[3][r] *= corr;
    }
    // P V  (A from Pl, B from Vt[d][key])
    const bf16x8 ap0 = *(const bf16x8*)(&Pl[wave][l15 * 72 + l4 * 8]);
    const bf16x8 ap1 = *(const bf16x8*)(&Pl[wave][l15 * 72 + 32 + l4 * 8]);
    #pragma unroll
    for (int dn = 0; dn < 4; ++dn) {
      const int r = dn * 16 + l15;
      bf16x8 bv0 = *(const bf16x8*)(Vt + r * 72 + l4 * 8);
      bf16x8 bv1 = *(const bf16x8*)(Vt + r * 72 + 32 + l4 * 8);
      o[dn] = __builtin_amdgcn_mfma_f32_16x16x32_bf16(ap0, bv0, o[dn], 0, 0, 0);
      o[dn] = __builtin_amdgcn_mfma_f32_16x16x32_bf16(ap1, bv1, o[dn], 0, 0, 0);
    }
    __syncthreads();
  }

  #pragma unroll
  for (int r = 0; r < 4; ++r) {
    const float inv = 1.0f / lrun[r];
    const int gq = tok0 + qt * 64 + wave * 16 + l4 * 4 + r;
    #pragma unroll
    for (int dn = 0; dn < 4; ++dn)
      hb[(size_t)gq * 5120 + d0 + dn * 16 + l15] = (bf16_t)(o[dn][r] * inv);
  }
}

// ---------------------------------------------------------------- final combine + tuple outputs
__global__ __launch_bounds__(256)
void final_kernel(const float* __restrict__ z, const float* __restrict__ x,
                  const int* __restrict__ em, const float* __restrict__ rp,
                  const float* __restrict__ alpha, float* __restrict__ out) {
  const int row = blockIdx.x, tid = threadIdx.x;
  const int e = em[row];
  const int dout = 2048 >> (3 - e);
  const float f = alpha[0] * rp[row * 4 + e] + 1.0f;
  const float* zr = z + (size_t)row * 2048;
  const float4 z0 = ((const float4*)zr)[tid];
  const float4 z1 = ((const float4*)(zr + 1024))[tid];
  const float4 xv = ((const float4*)(x + (size_t)row * 1024))[tid];
  const int c = tid * 4;
  float4 o;
  o.x = ((c + 0) < dout ? z0.x : 0.f) + xv.x + f * ((1024 + c + 0) < dout ? z1.x : 0.f);
  o.y = ((c + 1) < dout ? z0.y : 0.f) + xv.y + f * ((1024 + c + 1) < dout ? z1.y : 0.f);
  o.z = ((c + 2) < dout ? z0.z : 0.f) + xv.z + f * ((1024 + c + 2) < dout ? z1.z : 0.f);
  o.w = ((c + 3) < dout ? z0.w : 0.f) + xv.w + f * ((1024 + c + 3) < dout ? z1.w : 0.f);
  ((float4*)(out + (size_t)row * 1024))[tid] = o;
  float* out_em = out + 8388608;
  float* out_rp = out_em + 8192;
  if (tid == 0) out_em[row] = (float)e;
  if (tid < 4) out_rp[row * 4 + tid] = rp[row * 4 + tid];
}

// ---------------------------------------------------------------- launch
extern "C" void kernel_launch(void* const* d_in, const int* in_sizes, int n_in,
                              void* d_out, int out_size, void* d_ws, size_t ws_size,
                              hipStream_t stream) {
  const float* x = (const float*)d_in[0];
  const int* em = (const int*)d_in[1];
  const float* rp = (const float*)d_in[2];
  const float* w_exp = (const float*)d_in[3];
  const float* mlp_bias = (const float*)d_in[4];
  const float* w_con = (const float*)d_in[5];
  const float* c_bias = (const float*)d_in[6];
  const float* n1g = (const float*)d_in[7];
  const float* n1b = (const float*)d_in[8];
  const float* n2g = (const float*)d_in[9];
  const float* n2b = (const float*)d_in[10];
  const float* alpha = (const float*)d_in[11];

  char* ws = (char*)d_ws;
  // layout (bytes): Wexp 14,680,064 | xn 16,777,216 | q 16,777,216 | kv 33,554,432 | Wcon 20,971,520 | h 83,886,080
  // z (fp32, 67,108,864) aliases [xn|q|kv] (all dead before GEMM2). Total ws: 186,646,528 B.
  bf16_t* Wexp = (bf16_t*)ws;
  bf16_t* xn   = (bf16_t*)(ws + 14680064);
  bf16_t* qb   = (bf16_t*)(ws + 14680064 + 16777216);
  bf16_t* kvb  = (bf16_t*)(ws + 14680064 + 33554432);
  bf16_t* Wcon = (bf16_t*)(ws + 14680064 + 67108864);
  bf16_t* hb   = (bf16_t*)(ws + 14680064 + 67108864 + 20971520);
  float*  z    = (float*)(ws + 14680064);  // alias

  cast_kernel<<<7168, 256, 0, stream>>>(w_exp, Wexp, 7340032);
  cast_kernel<<<10240, 256, 0, stream>>>(w_con, Wcon, 10485760);
  ln1_kernel<<<8192, 256, 0, stream>>>(x, n1g, n1b, em, xn);
  gemm_bt<0><<<dim3(64, 56), 256, 0, stream>>>(xn, Wexp, 1024, mlp_bias, qb, kvb, hb, nullptr);
  ln2_kernel<<<8192, 256, 0, stream>>>(kvb, n2g, n2b);
  attn_kernel<<<dim3(16, 128), 256, 0, stream>>>(qb, kvb, hb);
  gemm_bt<1><<<dim3(64, 16), 256, 0, stream>>>(hb, Wcon, 5120, c_bias, nullptr, nullptr, nullptr, z);
  final_kernel<<<8192, 256, 0, stream>>>(z, x, em, rp, alpha, (float*)d_out);
}